// Round 6
// baseline (2077.324 us; speedup 1.0000x reference)
//
#include <hip/hip_runtime.h>
#include <hip/hip_bf16.h>

typedef __bf16 bf16x8 __attribute__((ext_vector_type(8)));
typedef float f32x4 __attribute__((ext_vector_type(4)));
typedef float f32x4u __attribute__((ext_vector_type(4), aligned(4)));

#define NH 12
#define HD 64
#define SEQ 145
#define SP 160
#define DMODEL 768
#define NTOT 2304
#define BDIM 1024
#define RBS 148   // rbias padded row stride (multiple of 4 for aligned float4)

// f32 -> bf16 RNE
__device__ __forceinline__ ushort f2bf(float f) {
  union { float f; uint u; } a; a.f = f;
  uint u = a.u;
  return (ushort)((u + 0x7FFFu + ((u >> 16) & 1u)) >> 16);
}

__device__ __forceinline__ int relidx(int qi, int ki) {
  if (ki == 0) return (qi == 0) ? 531 : 530;
  if (qi == 0) return 529;
  int q = qi - 1, k = ki - 1;
  int qh = q / 12, qw = q - qh * 12;
  int kh = k / 12, kw = k - kh * 12;
  return (qh - kh + 11) * 23 + (qw - kw + 11);
}

// async global->LDS, 16B per lane; lds dest = wave-uniform base + lane*16
__device__ __forceinline__ void gload_lds16(const ushort* g, ushort* l) {
  __builtin_amdgcn_global_load_lds(
      (const __attribute__((address_space(1))) void*)g,
      (__attribute__((address_space(3))) void*)l, 16, 0, 0);
}

#define VMCNT(n) do { asm volatile("s_waitcnt vmcnt(" #n ")" ::: "memory"); \
                      __builtin_amdgcn_sched_barrier(0); } while (0)

// ---------------- prep: Wt[n][k] = W_sel[k][n%768] as bf16 ----------------
__global__ void prep_w(const float* __restrict__ Wq, const float* __restrict__ Wk,
                       const float* __restrict__ Wv, ushort* __restrict__ Wt) {
  int i = blockIdx.x * 256 + threadIdx.x;
  if (i >= NTOT * DMODEL) return;
  int n = i / DMODEL, k = i - n * DMODEL;
  const float* W = (n < DMODEL) ? Wq : (n < 2 * DMODEL ? Wk : Wv);
  int c = n % DMODEL;
  Wt[i] = f2bf(W[k * DMODEL + c]);
}

// ---------------- x f32 -> bf16 (into d_out scratch) ----------------
__global__ void x2bf(const float* __restrict__ x, ushort* __restrict__ xb) {
  const size_t total = (size_t)BDIM * SEQ * DMODEL;
  size_t i = ((size_t)blockIdx.x * 256 + threadIdx.x) * 8;
  if (i >= total) return;
  float4 a = *reinterpret_cast<const float4*>(x + i);
  float4 c = *reinterpret_cast<const float4*>(x + i + 4);
  uint4 o;
  o.x = (uint)f2bf(a.x) | ((uint)f2bf(a.y) << 16);
  o.y = (uint)f2bf(a.z) | ((uint)f2bf(a.w) << 16);
  o.z = (uint)f2bf(c.x) | ((uint)f2bf(c.y) << 16);
  o.w = (uint)f2bf(c.z) | ((uint)f2bf(c.w) << 16);
  *reinterpret_cast<uint4*>(xb + i) = o;
}

// ---------------- zero pad region of transposed V buffer ----------------
__global__ void zero_vpad(ushort* __restrict__ vbuf) {
  int i = blockIdx.x * 256 + threadIdx.x;
  const int total = BDIM * NH * HD * (SP - SEQ);
  if (i >= total) return;
  int s = SEQ + i % (SP - SEQ);
  int row = i / (SP - SEQ);
  vbuf[(size_t)row * SP + s] = 0;
}

// ---------------- rel bias table: rbias[h][qi][ki], row stride RBS ----------------
__global__ void rel_prep(const float* __restrict__ tbl, float* __restrict__ rbias) {
  int i = blockIdx.x * 256 + threadIdx.x;
  if (i >= NH * SEQ * RBS) return;
  int h = i / (SEQ * RBS);
  int rem = i - h * SEQ * RBS;
  int qi = rem / RBS, ki = rem - qi * RBS;
  rbias[i] = (ki < SEQ) ? tbl[relidx(qi, ki) * NH + h] : 0.f;
}

// ---------------- fused QKV GEMM: [148480,768] x [768,2304] ----------------
// 256x256 tile, BK=64 as 2 k-chunks of 32; 8 waves (2x4); 128 KB LDS dbuf;
// next K-tile staged entirely at phase 0 (lead 4-5 phases), counted vmcnt.
#define GNT 9
#define GNWG 5220   // 580 * 9

__global__ __launch_bounds__(512, 2)
void qkv_gemm(const ushort* __restrict__ xb, const ushort* __restrict__ Wt,
              const float* __restrict__ bq, const float* __restrict__ bv,
              ushort* __restrict__ qbuf, ushort* __restrict__ kbuf,
              ushort* __restrict__ vbuf) {
  __shared__ __align__(16) ushort lds[65536];   // 128 KB

  // bijective XCD swizzle (m204): nwg=5220, q=652, r=4
  int bid = blockIdx.x;
  int xcd = bid & 7;
  int j = bid >> 3;
  int logical = (xcd < 4 ? xcd * 653 : 4 * 653 + (xcd - 4) * 652) + j;
  int mt = logical / GNT, nt = logical - (logical / GNT) * GNT;
  int m0 = mt * 256, n0 = nt * 256;

  int tid = threadIdx.x;
  int l = tid & 63, w = tid >> 6;
  int wm = w >> 2, wn = w & 3;
  int l15 = l & 15, l4 = l >> 4;
  int rslot = l4 ^ ((l15 >> 1) & 3);

  // staging source pointers (per-lane, inverse-swizzled)
  int srow = (w << 4) + (l >> 2);
  int sslot = (l & 3) ^ ((l >> 3) & 3);
  const ushort* aSrc0 = xb + (size_t)(m0 + srow) * DMODEL + sslot * 8;
  const ushort* aSrc1 = xb + (size_t)(m0 + 128 + srow) * DMODEL + sslot * 8;
  const ushort* bSrc0 = Wt + (size_t)(n0 + srow) * DMODEL + sslot * 8;
  const ushort* bSrc1 = Wt + (size_t)(n0 + 128 + srow) * DMODEL + sslot * 8;
  int wb16 = (w << 4) << 5;   // (w*16)<<5

#define STAGE_A(db, kc, kof) do { \
    gload_lds16(aSrc0 + (kof), &lds[(((db)*2+(kc))<<13) + wb16]); \
    gload_lds16(aSrc1 + (kof), &lds[(((db)*2+(kc))<<13) + (128<<5) + wb16]); \
  } while (0)
#define STAGE_B(db, kc, kof) do { \
    gload_lds16(bSrc0 + (kof), &lds[32768 + (((db)*2+(kc))<<13) + wb16]); \
    gload_lds16(bSrc1 + (kof), &lds[32768 + (((db)*2+(kc))<<13) + (128<<5) + wb16]); \
  } while (0)

  f32x4 acc[8][4];
  #pragma unroll
  for (int m = 0; m < 8; m++)
    #pragma unroll
    for (int n = 0; n < 4; n++)
      #pragma unroll
      for (int e = 0; e < 4; e++) acc[m][n][e] = 0.f;

  bf16x8 af[8], bfr[2];

#define LOAD_A(db, kk) do { int base_ = ((db)*2+(kk))<<13; \
    _Pragma("unroll") \
    for (int mf_ = 0; mf_ < 8; mf_++) \
      af[mf_] = *reinterpret_cast<const bf16x8*>( \
          &lds[base_ + ((wm*128 + mf_*16 + l15) << 5) + rslot*8]); \
  } while (0)
#define LOAD_B(db, nq, kk) do { int base_ = 32768 + (((db)*2+(kk))<<13); \
    _Pragma("unroll") \
    for (int nf_ = 0; nf_ < 2; nf_++) \
      bfr[nf_] = *reinterpret_cast<const bf16x8*>( \
          &lds[base_ + ((wn*64 + (nq)*32 + nf_*16 + l15) << 5) + rslot*8]); \
  } while (0)
#define MFMA16(nq) do { \
    __builtin_amdgcn_s_setprio(1); \
    _Pragma("unroll") \
    for (int mf_ = 0; mf_ < 8; mf_++) { \
      acc[mf_][(nq)*2+0] = __builtin_amdgcn_mfma_f32_16x16x32_bf16(af[mf_], bfr[0], acc[mf_][(nq)*2+0], 0, 0, 0); \
      acc[mf_][(nq)*2+1] = __builtin_amdgcn_mfma_f32_16x16x32_bf16(af[mf_], bfr[1], acc[mf_][(nq)*2+1], 0, 0, 0); \
    } \
    __builtin_amdgcn_s_setprio(0); \
  } while (0)

  // prologue: stage K-tile 0 fully (8 loads)
  STAGE_A(0, 0, 0); STAGE_B(0, 0, 0);
  STAGE_A(0, 1, 32); STAGE_B(0, 1, 32);
  VMCNT(4);
  __builtin_amdgcn_s_barrier();

  for (int kt = 0; kt < 12; ++kt) {
    int db = kt & 1, dn = db ^ 1;
    int kof = (kt + 1) * 64;
    // ---- phase 0: issue ALL of tile kt+1; compute (nq0, kk0) ----
    if (kt < 11) {
      STAGE_A(dn, 0, kof);      STAGE_B(dn, 0, kof);
      STAGE_A(dn, 1, kof + 32); STAGE_B(dn, 1, kof + 32);
    }
    LOAD_A(db, 0); LOAD_B(db, 0, 0);
    __builtin_amdgcn_s_barrier();
    MFMA16(0);
    // ---- phase 1: nq=1, kk=0 ----
    LOAD_B(db, 1, 0);
    if (kt < 11) { VMCNT(8); } else { VMCNT(0); }   // retire this tile's k1 chunks
    __builtin_amdgcn_s_barrier();
    MFMA16(1);
    // ---- phase 2: nq=0, kk=1 ----
    LOAD_A(db, 1); LOAD_B(db, 0, 1);
    __builtin_amdgcn_s_barrier();
    MFMA16(0);
    // ---- phase 3: nq=1, kk=1 ----
    LOAD_B(db, 1, 1);
    if (kt < 11) { VMCNT(4); }                      // retire next tile's k0 chunks
    __builtin_amdgcn_s_barrier();
    MFMA16(1);
  }

  // epilogue: which sub-matrix (q/k/v) is uniform per block (768 % 256 == 0)
  int which = n0 / DMODEL;
  #pragma unroll
  for (int nn = 0; nn < 4; nn++) {
    int col = n0 + wn * 64 + nn * 16 + l15;
    int hcol = col - which * DMODEL;
    int h = hcol >> 6, dh = hcol & 63;
    float bias = (which == 0) ? bq[hcol] : (which == 2 ? bv[hcol] : 0.f);
    #pragma unroll
    for (int mf = 0; mf < 8; mf++) {
      int rowb = m0 + wm * 128 + mf * 16 + (l4 << 2);
      #pragma unroll
      for (int r = 0; r < 4; r++) {
        int row = rowb + r;
        int b = row / SEQ;
        int s = row - b * SEQ;
        float v = acc[mf][nn][r] + bias;
        size_t bh = (size_t)b * NH + h;
        if (which == 0) {
          v *= 0.125f;  // fold 1/sqrt(64)
          qbuf[(bh * SEQ + s) * HD + dh] = f2bf(v);
        } else if (which == 1) {
          kbuf[(bh * SEQ + s) * HD + dh] = f2bf(v);
        } else {
          vbuf[(bh * HD + dh) * SP + s] = f2bf(v);  // transposed + padded
        }
      }
    }
  }
#undef STAGE_A
#undef STAGE_B
#undef LOAD_A
#undef LOAD_B
#undef MFMA16
}

// ---------------- fused windowed attention (swapped QK: S[ki][qi]) ----------------
// block = (b, strip); 256 thr = 4 waves, each wave runs 3 heads sequentially.
// Swapped mfma(K,Q) makes each lane hold 4 consecutive ki for one qi ->
// mask/rbias become float4 loads. Mask strip in LDS shared by all 12 heads.
__global__ __launch_bounds__(256, 5)
void attn_kernel(const ushort* __restrict__ qbuf, const ushort* __restrict__ kbuf,
                 const ushort* __restrict__ vbuf, const float* __restrict__ mask,
                 const float* __restrict__ rbias, float* __restrict__ out) {
  __shared__ float mlds[16][164];                       // 10.5 KB mask strip
  __shared__ __align__(16) ushort plds[4][16][SP + 8];  // per-wave P, 21.5 KB

  int i = blockIdx.x;
  int xcd = i & 7;
  int j = i >> 3;                 // 0..1279
  int b = xcd + 8 * (j / 10);     // b % 8 == xcd (mask/K/V L2 affinity)
  int strip = j % 10;
  int r0 = strip * 16;

  int tid = threadIdx.x;
  int lane = tid & 63, w = tid >> 6;
  int l15 = lane & 15, l4 = lane >> 4;

  const float* mp = mask + (size_t)b * SEQ * SEQ;

  // stage mask strip [16][164] (rows clamped, cols>=SEQ set to -3e38)
  for (int idx = tid; idx < 16 * 164; idx += 256) {
    int row = idx / 164, col = idx - row * 164;
    int gr = r0 + row; if (gr >= SEQ) gr = SEQ - 1;
    mlds[row][col] = (col < SEQ) ? mp[gr * SEQ + col] : -3e38f;
  }
  __syncthreads();

  int qi = r0 + l15;                       // this lane's query row
  int qc = (qi < SEQ) ? qi : (SEQ - 1);
  bool qok = (qi < SEQ);

  #pragma unroll 1
  for (int hh = 0; hh < 3; hh++) {
    int h = w + hh * 4;
    int bh = b * NH + h;
    const ushort* qp = qbuf + (size_t)bh * SEQ * HD;
    const ushort* kp = kbuf + (size_t)bh * SEQ * HD;
    const ushort* vp = vbuf + (size_t)bh * HD * SP;
    const float* rp = rbias + (size_t)h * SEQ * RBS + (size_t)qc * RBS;

    // Q as the B-operand (col = qi)
    bf16x8 qf[2];
    if (qok) {
      qf[0] = *reinterpret_cast<const bf16x8*>(qp + qi * HD + l4 * 8);
      qf[1] = *reinterpret_cast<const bf16x8*>(qp + qi * HD + 32 + l4 * 8);
    } else {
      uint4 z = make_uint4(0, 0, 0, 0);
      qf[0] = *reinterpret_cast<bf16x8*>(&z);
      qf[1] = *reinterpret_cast<bf16x8*>(&z);
    }

    // scores: swapped mfma(K, Q) -> C[ki][qi]; lane: 4 consecutive ki per reg
    f32x4 sc[10];
    #pragma unroll
    for (int ct = 0; ct < 10; ct++)
      #pragma unroll
      for (int e = 0; e < 4; e++) sc[ct][e] = 0.f;
    #pragma unroll
    for (int ct = 0; ct < 10; ct++) {
      int krow = ct * 16 + l15;
      if (krow >= SEQ) krow = 0;   // clamp: real data, masked below
      bf16x8 kf0 = *reinterpret_cast<const bf16x8*>(kp + krow * HD + l4 * 8);
      bf16x8 kf1 = *reinterpret_cast<const bf16x8*>(kp + krow * HD + 32 + l4 * 8);
      sc[ct] = __builtin_amdgcn_mfma_f32_16x16x32_bf16(kf0, qf[0], sc[ct], 0, 0, 0);
      sc[ct] = __builtin_amdgcn_mfma_f32_16x16x32_bf16(kf1, qf[1], sc[ct], 0, 0, 0);
    }

    // add mask (LDS float4) + rel bias (global float4); per-lane max over ki
    float mx = -3e38f;
    #pragma unroll
    for (int ct = 0; ct < 10; ct++) {
      int kb = ct * 16 + l4 * 4;
      f32x4u rb = *reinterpret_cast<const f32x4u*>(rp + kb);
      f32x4u mk = *reinterpret_cast<const f32x4u*>(&mlds[l15][kb]);
      #pragma unroll
      for (int r = 0; r < 4; r++) {
        int ki = kb + r;
        float v = sc[ct][r] + mk[r] + rb[r];
        float sv = (ki < SEQ && qok) ? v : -3e38f;
        sc[ct][r] = sv;
        mx = fmaxf(mx, sv);
      }
    }
    mx = fmaxf(mx, __shfl_xor(mx, 16, 64));
    mx = fmaxf(mx, __shfl_xor(mx, 32, 64));

    // exp + sum over ki
    float sum = 0.f;
    #pragma unroll
    for (int ct = 0; ct < 10; ct++)
      #pragma unroll
      for (int r = 0; r < 4; r++) {
        float p = __expf(sc[ct][r] - mx);
        sc[ct][r] = p;
        sum += p;
      }
    sum += __shfl_xor(sum, 16, 64);
    sum += __shfl_xor(sum, 32, 64);
    float inv = 1.f / sum;

    // P (bf16) to per-wave LDS: row = qi-idx (l15), cols = ki; ushort4 stores
    #pragma unroll
    for (int ct = 0; ct < 10; ct++) {
      ushort4 pk;
      pk.x = f2bf(sc[ct][0] * inv);
      pk.y = f2bf(sc[ct][1] * inv);
      pk.z = f2bf(sc[ct][2] * inv);
      pk.w = f2bf(sc[ct][3] * inv);
      *reinterpret_cast<ushort4*>(&plds[w][l15][ct * 16 + l4 * 4]) = pk;
    }

    // PV: ctx[16 x 64]; V^T direct from global (pad cols zeroed)
    #pragma unroll
    for (int ntl = 0; ntl < 4; ntl++) {
      f32x4 pacc;
      #pragma unroll
      for (int e = 0; e < 4; e++) pacc[e] = 0.f;
      #pragma unroll
      for (int ks = 0; ks < 5; ks++) {
        bf16x8 pa = *reinterpret_cast<const bf16x8*>(
            &plds[w][l15][ks * 32 + l4 * 8]);
        bf16x8 vb = *reinterpret_cast<const bf16x8*>(
            vp + (ntl * 16 + l15) * SP + ks * 32 + l4 * 8);
        pacc = __builtin_amdgcn_mfma_f32_16x16x32_bf16(pa, vb, pacc, 0, 0, 0);
      }
      #pragma unroll
      for (int r = 0; r < 4; r++) {
        int s = r0 + l4 * 4 + r;
        if (s < SEQ)
          out[((size_t)b * SEQ + s) * DMODEL + h * HD + ntl * 16 + l15] = pacc[r];
      }
    }
  }
}

extern "C" void kernel_launch(void* const* d_in, const int* in_sizes, int n_in,
                              void* d_out, int out_size, void* d_ws, size_t ws_size,
                              hipStream_t stream) {
  const float* x    = (const float*)d_in[0];
  const float* mask = (const float*)d_in[1];
  const float* Wq   = (const float*)d_in[2];
  const float* bq   = (const float*)d_in[3];
  const float* Wk   = (const float*)d_in[4];
  const float* Wv   = (const float*)d_in[5];
  const float* bv   = (const float*)d_in[6];
  const float* tbl  = (const float*)d_in[7];
  float* out = (float*)d_out;

  char* ws = (char*)d_ws;
  ushort* Wt = (ushort*)ws;                         // 3,538,944 B
  size_t off = (size_t)NTOT * DMODEL * 2;
  ushort* qbuf = (ushort*)(ws + off); off += (size_t)BDIM * NH * SEQ * HD * 2;
  ushort* kbuf = (ushort*)(ws + off); off += (size_t)BDIM * NH * SEQ * HD * 2;
  ushort* vbuf = (ushort*)(ws + off); off += (size_t)BDIM * NH * HD * SP * 2;
  float*  rbias = (float*)(ws + off); off += (size_t)NH * SEQ * RBS * 4 + 64;
  // ~713 MB of d_ws

  // bf16 x lives in d_out scratch (456 MB f32 out >= 228 MB bf16 x);
  // attn_kernel later overwrites every element of d_out.
  ushort* xbuf = (ushort*)d_out;

  prep_w<<<(NTOT * DMODEL + 255) / 256, 256, 0, stream>>>(Wq, Wk, Wv, Wt);
  zero_vpad<<<(BDIM * NH * HD * (SP - SEQ) + 255) / 256, 256, 0, stream>>>(vbuf);
  rel_prep<<<(NH * SEQ * RBS + 255) / 256, 256, 0, stream>>>(tbl, rbias);
  {
    size_t total = (size_t)BDIM * SEQ * DMODEL;
    x2bf<<<(int)(total / 8 / 256), 256, 0, stream>>>(x, xbuf);
  }

  qkv_gemm<<<GNWG, 512, 0, stream>>>(xbuf, Wt, bq, bv, qbuf, kbuf, vbuf);

  attn_kernel<<<BDIM * 10, 256, 0, stream>>>(qbuf, kbuf, vbuf, mask, rbias, out);
}

// Round 7
// 1713.604 us; speedup vs baseline: 1.2123x; 1.2123x over previous
//
#include <hip/hip_runtime.h>
#include <hip/hip_bf16.h>

typedef __bf16 bf16x8 __attribute__((ext_vector_type(8)));
typedef float f32x4 __attribute__((ext_vector_type(4)));
typedef float f32x4u __attribute__((ext_vector_type(4), aligned(4)));

#define NH 12
#define HD 64
#define SEQ 145
#define SP 160
#define DMODEL 768
#define NTOT 2304
#define BDIM 1024
#define RBS 148   // rbias padded row stride

// f32 -> bf16 RNE
__device__ __forceinline__ ushort f2bf(float f) {
  union { float f; uint u; } a; a.f = f;
  uint u = a.u;
  return (ushort)((u + 0x7FFFu + ((u >> 16) & 1u)) >> 16);
}

__device__ __forceinline__ int relidx(int qi, int ki) {
  if (ki == 0) return (qi == 0) ? 531 : 530;
  if (qi == 0) return 529;
  int q = qi - 1, k = ki - 1;
  int qh = q / 12, qw = q - qh * 12;
  int kh = k / 12, kw = k - kh * 12;
  return (qh - kh + 11) * 23 + (qw - kw + 11);
}

// async global->LDS, 16B per lane; lds dest = wave-uniform base + lane*16
__device__ __forceinline__ void gload_lds16(const ushort* g, ushort* l) {
  __builtin_amdgcn_global_load_lds(
      (const __attribute__((address_space(1))) void*)g,
      (__attribute__((address_space(3))) void*)l, 16, 0, 0);
}

#define VMCNT(n) do { asm volatile("s_waitcnt vmcnt(" #n ")" ::: "memory"); \
                      __builtin_amdgcn_sched_barrier(0); } while (0)

// ---------------- prep: Wt[n][k] = W_sel[k][n%768] as bf16 ----------------
__global__ void prep_w(const float* __restrict__ Wq, const float* __restrict__ Wk,
                       const float* __restrict__ Wv, ushort* __restrict__ Wt) {
  int i = blockIdx.x * 256 + threadIdx.x;
  if (i >= NTOT * DMODEL) return;
  int n = i / DMODEL, k = i - n * DMODEL;
  const float* W = (n < DMODEL) ? Wq : (n < 2 * DMODEL ? Wk : Wv);
  int c = n % DMODEL;
  Wt[i] = f2bf(W[k * DMODEL + c]);
}

// ---------------- x f32 -> bf16 (into d_out scratch) ----------------
__global__ void x2bf(const float* __restrict__ x, ushort* __restrict__ xb) {
  const size_t total = (size_t)BDIM * SEQ * DMODEL;
  size_t i = ((size_t)blockIdx.x * 256 + threadIdx.x) * 8;
  if (i >= total) return;
  float4 a = *reinterpret_cast<const float4*>(x + i);
  float4 c = *reinterpret_cast<const float4*>(x + i + 4);
  uint4 o;
  o.x = (uint)f2bf(a.x) | ((uint)f2bf(a.y) << 16);
  o.y = (uint)f2bf(a.z) | ((uint)f2bf(a.w) << 16);
  o.z = (uint)f2bf(c.x) | ((uint)f2bf(c.y) << 16);
  o.w = (uint)f2bf(c.z) | ((uint)f2bf(c.w) << 16);
  *reinterpret_cast<uint4*>(xb + i) = o;
}

// ---------------- zero pad region of transposed V buffer ----------------
__global__ void zero_vpad(ushort* __restrict__ vbuf) {
  int i = blockIdx.x * 256 + threadIdx.x;
  const int total = BDIM * NH * HD * (SP - SEQ);
  if (i >= total) return;
  int s = SEQ + i % (SP - SEQ);
  int row = i / (SP - SEQ);
  vbuf[(size_t)row * SP + s] = 0;
}

// ---------------- rel bias table: rbias[h][qi][ki], row stride RBS ----------------
__global__ void rel_prep(const float* __restrict__ tbl, float* __restrict__ rbias) {
  int i = blockIdx.x * 256 + threadIdx.x;
  if (i >= NH * SEQ * RBS) return;
  int h = i / (SEQ * RBS);
  int rem = i - h * SEQ * RBS;
  int qi = rem / RBS, ki = rem - qi * RBS;
  rbias[i] = (ki < SEQ) ? tbl[relidx(qi, ki) * NH + h] : 0.f;
}

// ---------------- fused QKV GEMM: [148480,768] x [768,2304] ----------------
// 256x256 tile, persistent over MT=4 M-panels (48 K-tiles continuous).
// 8 waves (2x4); 128 KB LDS dbuf; 4 balanced phases/K-tile, double barrier,
// interleaved staging (2 loads/phase), counted vmcnt(4), src/read swizzle.
#define GNT 9
#define GMT 4
#define GNWG 1305   // (580/4) * 9

__global__ __launch_bounds__(512, 2)
void qkv_gemm(const ushort* __restrict__ xb, const ushort* __restrict__ Wt,
              const float* __restrict__ bq, const float* __restrict__ bv,
              ushort* __restrict__ qbuf, ushort* __restrict__ kbuf,
              ushort* __restrict__ vbuf) {
  __shared__ __align__(16) ushort lds[65536];   // 128 KB

  // bijective XCD swizzle (m204): nwg=1305, q=163, r=1
  int bid = blockIdx.x;
  int xcd = bid & 7;
  int j = bid >> 3;
  int logical = (xcd < 1 ? 0 : 164 + (xcd - 1) * 163) + j;
  int mtg = logical / GNT, nt = logical - (logical / GNT) * GNT;
  int m0 = mtg * (256 * GMT), n0 = nt * 256;

  int tid = threadIdx.x;
  int l = tid & 63, w = tid >> 6;
  int wm = w >> 2, wn = w & 3;
  int l15 = l & 15, l4 = l >> 4;
  int rslot = l4 ^ ((l15 >> 1) & 3);

  // staging source pointers (per-lane, inverse-swizzled)
  int srow = (w << 4) + (l >> 2);
  int sslot = (l & 3) ^ ((l >> 3) & 3);
  const ushort* aSrc0 = xb + (size_t)(m0 + srow) * DMODEL + sslot * 8;
  const ushort* aSrc1 = xb + (size_t)(m0 + 128 + srow) * DMODEL + sslot * 8;
  const ushort* bSrc0 = Wt + (size_t)(n0 + srow) * DMODEL + sslot * 8;
  const ushort* bSrc1 = Wt + (size_t)(n0 + 128 + srow) * DMODEL + sslot * 8;
  int wb16 = (w << 4) << 5;   // (w*16)<<5

#define STAGE_A(bsel, aoff) do { \
    gload_lds16(aSrc0 + (aoff), &lds[((bsel) << 13) + wb16]); \
    gload_lds16(aSrc1 + (aoff), &lds[((bsel) << 13) + (128 << 5) + wb16]); \
  } while (0)
#define STAGE_B(bsel, boff) do { \
    gload_lds16(bSrc0 + (boff), &lds[32768 + ((bsel) << 13) + wb16]); \
    gload_lds16(bSrc1 + (boff), &lds[32768 + ((bsel) << 13) + (128 << 5) + wb16]); \
  } while (0)

  f32x4 acc[8][4];
  #pragma unroll
  for (int m = 0; m < 8; m++)
    #pragma unroll
    for (int n = 0; n < 4; n++)
      #pragma unroll
      for (int e = 0; e < 4; e++) acc[m][n][e] = 0.f;

  bf16x8 af[4], bfv[4];

#define LOAD_AF(bsel, mh) do { int base_ = (bsel) << 13; \
    _Pragma("unroll") \
    for (int i_ = 0; i_ < 4; i_++) \
      af[i_] = *reinterpret_cast<const bf16x8*>( \
          &lds[base_ + ((wm * 128 + (mh) * 64 + i_ * 16 + l15) << 5) + rslot * 8]); \
  } while (0)
#define LOAD_BFV(bsel) do { int base_ = 32768 + ((bsel) << 13); \
    _Pragma("unroll") \
    for (int n_ = 0; n_ < 4; n_++) \
      bfv[n_] = *reinterpret_cast<const bf16x8*>( \
          &lds[base_ + ((wn * 64 + n_ * 16 + l15) << 5) + rslot * 8]); \
  } while (0)
#define MFMA16(mh) do { \
    __builtin_amdgcn_s_setprio(1); \
    _Pragma("unroll") \
    for (int i_ = 0; i_ < 4; i_++) \
      _Pragma("unroll") \
      for (int n_ = 0; n_ < 4; n_++) \
        acc[(mh) * 4 + i_][n_] = __builtin_amdgcn_mfma_f32_16x16x32_bf16( \
            af[i_], bfv[n_], acc[(mh) * 4 + i_][n_], 0, 0, 0); \
    __builtin_amdgcn_s_setprio(0); \
  } while (0)

  // epilogue column metadata (uniform over t-loop)
  int which = n0 / DMODEL;
  int h_[4], dh_[4];
  float bias_[4];
  #pragma unroll
  for (int nn = 0; nn < 4; nn++) {
    int col = n0 + wn * 64 + nn * 16 + l15;
    int hcol = col - which * DMODEL;
    h_[nn] = hcol >> 6; dh_[nn] = hcol & 63;
    bias_[nn] = (which == 0) ? bq[hcol] : (which == 2 ? bv[hcol] : 0.f);
  }

  // prologue: stage tile 0 (panel 0, k0 & k1 chunks)
  STAGE_A(0, 0); STAGE_B(0, 0);
  STAGE_A(1, 32); STAGE_B(1, 32);
  VMCNT(4);
  __builtin_amdgcn_s_barrier();

  const int NT = 12 * GMT;          // 48 K-tiles total
  size_t aOff = 0;                  // current tile A row/k offset (ushorts)
  int bOff = 0;                     // current tile B k offset
  int ktc = 0;                      // K-tile index within panel
  int pp = 0;                       // panel index

  #pragma unroll 1
  for (int t = 0; t < NT; ++t) {
    int db = t & 1, dn = db ^ 1;
    int cb0 = db * 2, cb1 = db * 2 + 1;       // current buffers (k0,k1)
    int nb0 = dn * 2, nb1 = dn * 2 + 1;       // next-tile buffers
    size_t aOffN; int bOffN;
    if (ktc == 11) { aOffN = aOff + 64 + ((size_t)256 * DMODEL - 768); bOffN = 0; }
    else           { aOffN = aOff + 64; bOffN = bOff + 64; }

    // ---- P0: (kk0, mh0) ----
    if (t < NT - 1) STAGE_A(nb0, aOffN);
    LOAD_BFV(cb0); LOAD_AF(cb0, 0);
    __builtin_amdgcn_s_barrier();
    MFMA16(0);
    __builtin_amdgcn_s_barrier();
    // ---- P1: (kk0, mh1) ----
    if (t < NT - 1) STAGE_B(nb0, bOffN);
    LOAD_AF(cb0, 1);
    if (t < NT - 1) { VMCNT(4); } else { VMCNT(0); }   // retire this tile's k1
    __builtin_amdgcn_s_barrier();
    MFMA16(1);
    __builtin_amdgcn_s_barrier();
    // ---- P2: (kk1, mh0) ----
    if (t < NT - 1) STAGE_A(nb1, aOffN + 32);
    LOAD_BFV(cb1); LOAD_AF(cb1, 0);
    __builtin_amdgcn_s_barrier();
    MFMA16(0);
    __builtin_amdgcn_s_barrier();
    // ---- P3: (kk1, mh1) ----
    if (t < NT - 1) STAGE_B(nb1, bOffN + 32);
    LOAD_AF(cb1, 1);
    if (t < NT - 1) { VMCNT(4); }                      // retire next tile's k0
    __builtin_amdgcn_s_barrier();
    MFMA16(1);
    __builtin_amdgcn_s_barrier();

    aOff = aOffN; bOff = bOffN;

    if (ktc == 11) {
      // panel epilogue: flush acc (no LDS touched, no barrier needed)
      int m0c = m0 + pp * 256;
      #pragma unroll
      for (int mf = 0; mf < 8; mf++) {
        #pragma unroll
        for (int r = 0; r < 4; r++) {
          int row = m0c + wm * 128 + mf * 16 + (l4 << 2) + r;
          int bb = row / SEQ;
          int s = row - bb * SEQ;
          #pragma unroll
          for (int nn = 0; nn < 4; nn++) {
            float v = acc[mf][nn][r] + bias_[nn];
            size_t bh = (size_t)bb * NH + h_[nn];
            if (which == 0) {
              v *= 0.125f;
              qbuf[(bh * SEQ + s) * HD + dh_[nn]] = f2bf(v);
            } else if (which == 1) {
              kbuf[(bh * SEQ + s) * HD + dh_[nn]] = f2bf(v);
            } else {
              vbuf[(bh * HD + dh_[nn]) * SP + s] = f2bf(v);
            }
          }
        }
      }
      #pragma unroll
      for (int m = 0; m < 8; m++)
        #pragma unroll
        for (int n = 0; n < 4; n++)
          #pragma unroll
          for (int e = 0; e < 4; e++) acc[m][n][e] = 0.f;
      ktc = 0; pp++;
    } else {
      ktc++;
    }
  }
#undef STAGE_A
#undef STAGE_B
#undef LOAD_AF
#undef LOAD_BFV
#undef MFMA16
}

// ---------------- fused windowed attention (swapped QK, 12 waves = 12 heads) ----
// block = (b, 16-row strip); mask strip staged once, shared by all heads.
// XCD b-affinity: b % 8 == xcd (mask/K/V L2 reuse).
__global__ __launch_bounds__(768, 6)
void attn_kernel(const ushort* __restrict__ qbuf, const ushort* __restrict__ kbuf,
                 const ushort* __restrict__ vbuf, const float* __restrict__ mask,
                 const float* __restrict__ rbias, float* __restrict__ out) {
  __shared__ float mlds[16][164];                        // 10.5 KB mask strip
  __shared__ __align__(16) ushort plds[NH][16][SP + 8];  // per-wave P, 64.5 KB

  int i = blockIdx.x;
  int xcd = i & 7;
  int j = i >> 3;                 // 0..1279
  int b = xcd + 8 * (j / 10);     // b % 8 == xcd
  int strip = j % 10;
  int r0 = strip * 16;

  int tid = threadIdx.x;
  int lane = tid & 63, h = tid >> 6;   // wave id == head
  int l15 = lane & 15, l4 = lane >> 4;
  int bh = b * NH + h;

  const float* mp = mask + (size_t)b * SEQ * SEQ;

  // stage mask strip [16][164] (rows clamped, cols>=SEQ set to -3e38)
  for (int idx = tid; idx < 16 * 164; idx += 768) {
    int row = idx / 164, col = idx - row * 164;
    int gr = r0 + row; if (gr >= SEQ) gr = SEQ - 1;
    mlds[row][col] = (col < SEQ) ? mp[gr * SEQ + col] : -3e38f;
  }
  __syncthreads();

  int qi = r0 + l15;                       // this lane's query row
  int qc = (qi < SEQ) ? qi : (SEQ - 1);
  bool qok = (qi < SEQ);

  const ushort* qp = qbuf + (size_t)bh * SEQ * HD;
  const ushort* kp = kbuf + (size_t)bh * SEQ * HD;
  const ushort* vp = vbuf + (size_t)bh * HD * SP;
  const float* rp = rbias + (size_t)h * SEQ * RBS + (size_t)qc * RBS;

  // Q as the B-operand (col = qi)
  bf16x8 qf[2];
  if (qok) {
    qf[0] = *reinterpret_cast<const bf16x8*>(qp + qi * HD + l4 * 8);
    qf[1] = *reinterpret_cast<const bf16x8*>(qp + qi * HD + 32 + l4 * 8);
  } else {
    uint4 z = make_uint4(0, 0, 0, 0);
    qf[0] = *reinterpret_cast<bf16x8*>(&z);
    qf[1] = *reinterpret_cast<bf16x8*>(&z);
  }

  // scores: swapped mfma(K, Q) -> C[ki][qi]; lane holds 4 consecutive ki
  f32x4 sc[10];
  #pragma unroll
  for (int ct = 0; ct < 10; ct++)
    #pragma unroll
    for (int e = 0; e < 4; e++) sc[ct][e] = 0.f;
  #pragma unroll
  for (int ct = 0; ct < 10; ct++) {
    int krow = ct * 16 + l15;
    if (krow >= SEQ) krow = 0;   // clamp: real data, masked below
    bf16x8 kf0 = *reinterpret_cast<const bf16x8*>(kp + krow * HD + l4 * 8);
    bf16x8 kf1 = *reinterpret_cast<const bf16x8*>(kp + krow * HD + 32 + l4 * 8);
    sc[ct] = __builtin_amdgcn_mfma_f32_16x16x32_bf16(kf0, qf[0], sc[ct], 0, 0, 0);
    sc[ct] = __builtin_amdgcn_mfma_f32_16x16x32_bf16(kf1, qf[1], sc[ct], 0, 0, 0);
  }

  // add mask (LDS float4) + rel bias (global float4); per-lane max over ki
  float mx = -3e38f;
  #pragma unroll
  for (int ct = 0; ct < 10; ct++) {
    int kb = ct * 16 + l4 * 4;
    f32x4u rb = *reinterpret_cast<const f32x4u*>(rp + kb);
    f32x4u mk = *reinterpret_cast<const f32x4u*>(&mlds[l15][kb]);
    #pragma unroll
    for (int r = 0; r < 4; r++) {
      int ki = kb + r;
      float v = sc[ct][r] + mk[r] + rb[r];
      float sv = (ki < SEQ && qok) ? v : -3e38f;
      sc[ct][r] = sv;
      mx = fmaxf(mx, sv);
    }
  }
  mx = fmaxf(mx, __shfl_xor(mx, 16, 64));
  mx = fmaxf(mx, __shfl_xor(mx, 32, 64));

  // exp + sum over ki
  float sum = 0.f;
  #pragma unroll
  for (int ct = 0; ct < 10; ct++)
    #pragma unroll
    for (int r = 0; r < 4; r++) {
      float p = __expf(sc[ct][r] - mx);
      sc[ct][r] = p;
      sum += p;
    }
  sum += __shfl_xor(sum, 16, 64);
  sum += __shfl_xor(sum, 32, 64);
  float inv = 1.f / sum;

  // P (bf16) to per-wave LDS: row = qi idx (l15), cols = ki; ushort4 stores
  #pragma unroll
  for (int ct = 0; ct < 10; ct++) {
    ushort4 pk;
    pk.x = f2bf(sc[ct][0] * inv);
    pk.y = f2bf(sc[ct][1] * inv);
    pk.z = f2bf(sc[ct][2] * inv);
    pk.w = f2bf(sc[ct][3] * inv);
    *reinterpret_cast<ushort4*>(&plds[h][l15][ct * 16 + l4 * 4]) = pk;
  }

  // PV: ctx[16 x 64]; V^T direct from global (pad cols zeroed)
  #pragma unroll
  for (int ntl = 0; ntl < 4; ntl++) {
    f32x4 pacc;
    #pragma unroll
    for (int e = 0; e < 4; e++) pacc[e] = 0.f;
    #pragma unroll
    for (int ks = 0; ks < 5; ks++) {
      bf16x8 pa = *reinterpret_cast<const bf16x8*>(
          &plds[h][l15][ks * 32 + l4 * 8]);
      bf16x8 vb = *reinterpret_cast<const bf16x8*>(
          vp + (ntl * 16 + l15) * SP + ks * 32 + l4 * 8);
      pacc = __builtin_amdgcn_mfma_f32_16x16x32_bf16(pa, vb, pacc, 0, 0, 0);
    }
    #pragma unroll
    for (int r = 0; r < 4; r++) {
      int s = r0 + l4 * 4 + r;
      if (s < SEQ)
        out[((size_t)b * SEQ + s) * DMODEL + h * HD + ntl * 16 + l15] = pacc[r];
    }
  }
}

extern "C" void kernel_launch(void* const* d_in, const int* in_sizes, int n_in,
                              void* d_out, int out_size, void* d_ws, size_t ws_size,
                              hipStream_t stream) {
  const float* x    = (const float*)d_in[0];
  const float* mask = (const float*)d_in[1];
  const float* Wq   = (const float*)d_in[2];
  const float* bq   = (const float*)d_in[3];
  const float* Wk   = (const float*)d_in[4];
  const float* Wv   = (const float*)d_in[5];
  const float* bv   = (const float*)d_in[6];
  const float* tbl  = (const float*)d_in[7];
  float* out = (float*)d_out;

  char* ws = (char*)d_ws;
  ushort* Wt = (ushort*)ws;                         // 3,538,944 B
  size_t off = (size_t)NTOT * DMODEL * 2;
  ushort* qbuf = (ushort*)(ws + off); off += (size_t)BDIM * NH * SEQ * HD * 2;
  ushort* kbuf = (ushort*)(ws + off); off += (size_t)BDIM * NH * SEQ * HD * 2;
  ushort* vbuf = (ushort*)(ws + off); off += (size_t)BDIM * NH * HD * SP * 2;
  float*  rbias = (float*)(ws + off); off += (size_t)NH * SEQ * RBS * 4 + 64;
  // ~713 MB of d_ws

  // bf16 x lives in d_out scratch (456 MB f32 out >= 228 MB bf16 x);
  // attn_kernel later overwrites every element of d_out.
  ushort* xbuf = (ushort*)d_out;

  prep_w<<<(NTOT * DMODEL + 255) / 256, 256, 0, stream>>>(Wq, Wk, Wv, Wt);
  zero_vpad<<<(BDIM * NH * HD * (SP - SEQ) + 255) / 256, 256, 0, stream>>>(vbuf);
  rel_prep<<<(NH * SEQ * RBS + 255) / 256, 256, 0, stream>>>(tbl, rbias);
  {
    size_t total = (size_t)BDIM * SEQ * DMODEL;
    x2bf<<<(int)(total / 8 / 256), 256, 0, stream>>>(x, xbuf);
  }

  qkv_gemm<<<GNWG, 512, 0, stream>>>(xbuf, Wt, bq, bv, qbuf, kbuf, vbuf);

  attn_kernel<<<BDIM * 10, 768, 0, stream>>>(qbuf, kbuf, vbuf, mask, rbias, out);
}

// Round 9
// 1688.646 us; speedup vs baseline: 1.2302x; 1.0148x over previous
//
#include <hip/hip_runtime.h>
#include <hip/hip_bf16.h>

typedef __bf16 bf16x8 __attribute__((ext_vector_type(8)));
typedef float f32x4 __attribute__((ext_vector_type(4)));
typedef float f32x4u __attribute__((ext_vector_type(4), aligned(4)));

#define NH 12
#define HD 64
#define SEQ 145
#define SP 160
#define DMODEL 768
#define NTOT 2304
#define BDIM 1024
#define RBS 148   // rbias padded row stride (16B-aligned float4 rows)

// f32 -> bf16 RNE
__device__ __forceinline__ ushort f2bf(float f) {
  union { float f; uint u; } a; a.f = f;
  uint u = a.u;
  return (ushort)((u + 0x7FFFu + ((u >> 16) & 1u)) >> 16);
}

__device__ __forceinline__ int relidx(int qi, int ki) {
  if (ki == 0) return (qi == 0) ? 531 : 530;
  if (qi == 0) return 529;
  int q = qi - 1, k = ki - 1;
  int qh = q / 12, qw = q - qh * 12;
  int kh = k / 12, kw = k - kh * 12;
  return (qh - kh + 11) * 23 + (qw - kw + 11);
}

// async global->LDS, 16B per lane; lds dest = wave-uniform base + lane*16
__device__ __forceinline__ void gload_lds16(const ushort* g, ushort* l) {
  __builtin_amdgcn_global_load_lds(
      (const __attribute__((address_space(1))) void*)g,
      (__attribute__((address_space(3))) void*)l, 16, 0, 0);
}

#define VMCNT(n) do { asm volatile("s_waitcnt vmcnt(" #n ")" ::: "memory"); \
                      __builtin_amdgcn_sched_barrier(0); } while (0)

// ---------------- prep: Wt[n][k] = W_sel[k][n%768] as bf16 ----------------
__global__ void prep_w(const float* __restrict__ Wq, const float* __restrict__ Wk,
                       const float* __restrict__ Wv, ushort* __restrict__ Wt) {
  int i = blockIdx.x * 256 + threadIdx.x;
  if (i >= NTOT * DMODEL) return;
  int n = i / DMODEL, k = i - n * DMODEL;
  const float* W = (n < DMODEL) ? Wq : (n < 2 * DMODEL ? Wk : Wv);
  int c = n % DMODEL;
  Wt[i] = f2bf(W[k * DMODEL + c]);
}

// ---------------- x f32 -> bf16 (into d_out scratch) ----------------
__global__ void x2bf(const float* __restrict__ x, ushort* __restrict__ xb) {
  const size_t total = (size_t)BDIM * SEQ * DMODEL;
  size_t i = ((size_t)blockIdx.x * 256 + threadIdx.x) * 8;
  if (i >= total) return;
  float4 a = *reinterpret_cast<const float4*>(x + i);
  float4 c = *reinterpret_cast<const float4*>(x + i + 4);
  uint4 o;
  o.x = (uint)f2bf(a.x) | ((uint)f2bf(a.y) << 16);
  o.y = (uint)f2bf(a.z) | ((uint)f2bf(a.w) << 16);
  o.z = (uint)f2bf(c.x) | ((uint)f2bf(c.y) << 16);
  o.w = (uint)f2bf(c.z) | ((uint)f2bf(c.w) << 16);
  *reinterpret_cast<uint4*>(xb + i) = o;
}

// ---------------- zero pad region of transposed V buffer ----------------
__global__ void zero_vpad(ushort* __restrict__ vbuf) {
  int i = blockIdx.x * 256 + threadIdx.x;
  const int total = BDIM * NH * HD * (SP - SEQ);
  if (i >= total) return;
  int s = SEQ + i % (SP - SEQ);
  int row = i / (SP - SEQ);
  vbuf[(size_t)row * SP + s] = 0;
}

// ---------------- rel bias table: rbias[h][qi][ki], row stride RBS ----------------
__global__ void rel_prep(const float* __restrict__ tbl, float* __restrict__ rbias) {
  int i = blockIdx.x * 256 + threadIdx.x;
  if (i >= NH * SEQ * RBS) return;
  int h = i / (SEQ * RBS);
  int rem = i - h * SEQ * RBS;
  int qi = rem / RBS, ki = rem - qi * RBS;
  rbias[i] = (ki < SEQ) ? tbl[relidx(qi, ki) * NH + h] : 0.f;
}

// ---------------- fused QKV GEMM: [148480,768] x [768,2304] ----------------
// Round-4 proven schedule (897 us): 256x256 tile, BK=64 as 2 k-chunks of 32;
// 8 waves (2x4); 128 KB LDS dbuf; 4 phases/K-tile, interleaved staging,
// counted vmcnt(4), src/read swizzle (bank-conflict = 0).
#define GNT 9
#define GNWG 5220   // 580 * 9

__global__ __launch_bounds__(512, 2)
void qkv_gemm(const ushort* __restrict__ xb, const ushort* __restrict__ Wt,
              const float* __restrict__ bq, const float* __restrict__ bv,
              ushort* __restrict__ qbuf, ushort* __restrict__ kbuf,
              ushort* __restrict__ vbuf) {
  __shared__ __align__(16) ushort lds[65536];   // 128 KB

  // bijective XCD swizzle (m204): nwg=5220, q=652, r=4
  int bid = blockIdx.x;
  int xcd = bid & 7;
  int j = bid >> 3;
  int logical = (xcd < 4 ? xcd * 653 : 4 * 653 + (xcd - 4) * 652) + j;
  int mt = logical / GNT, nt = logical - (logical / GNT) * GNT;
  int m0 = mt * 256, n0 = nt * 256;

  int tid = threadIdx.x;
  int l = tid & 63, w = tid >> 6;
  int wm = w >> 2, wn = w & 3;
  int l15 = l & 15, l4 = l >> 4;
  int rslot = l4 ^ ((l15 >> 1) & 3);

  // staging source pointers (per-lane, inverse-swizzled)
  int srow = (w << 4) + (l >> 2);
  int sslot = (l & 3) ^ ((l >> 3) & 3);
  const ushort* aSrc0 = xb + (size_t)(m0 + srow) * DMODEL + sslot * 8;
  const ushort* aSrc1 = xb + (size_t)(m0 + 128 + srow) * DMODEL + sslot * 8;
  const ushort* bSrc0 = Wt + (size_t)(n0 + srow) * DMODEL + sslot * 8;
  const ushort* bSrc1 = Wt + (size_t)(n0 + 128 + srow) * DMODEL + sslot * 8;
  int wb16 = (w << 4) << 5;   // (w*16)<<5

#define STAGE_A(db, kc, kof) do { \
    gload_lds16(aSrc0 + (kof), &lds[(((db)*2+(kc))<<13) + wb16]); \
    gload_lds16(aSrc1 + (kof), &lds[(((db)*2+(kc))<<13) + (128<<5) + wb16]); \
  } while (0)
#define STAGE_B(db, kc, kof) do { \
    gload_lds16(bSrc0 + (kof), &lds[32768 + (((db)*2+(kc))<<13) + wb16]); \
    gload_lds16(bSrc1 + (kof), &lds[32768 + (((db)*2+(kc))<<13) + (128<<5) + wb16]); \
  } while (0)

  f32x4 acc[8][4];
  #pragma unroll
  for (int m = 0; m < 8; m++)
    #pragma unroll
    for (int n = 0; n < 4; n++)
      #pragma unroll
      for (int e = 0; e < 4; e++) acc[m][n][e] = 0.f;

  bf16x8 af[8], bfr[2];

#define LOAD_A(db, kk) do { int base_ = ((db)*2+(kk))<<13; \
    _Pragma("unroll") \
    for (int mf_ = 0; mf_ < 8; mf_++) \
      af[mf_] = *reinterpret_cast<const bf16x8*>( \
          &lds[base_ + ((wm*128 + mf_*16 + l15) << 5) + rslot*8]); \
  } while (0)
#define LOAD_B(db, nq, kk) do { int base_ = 32768 + (((db)*2+(kk))<<13); \
    _Pragma("unroll") \
    for (int nf_ = 0; nf_ < 2; nf_++) \
      bfr[nf_] = *reinterpret_cast<const bf16x8*>( \
          &lds[base_ + ((wn*64 + (nq)*32 + nf_*16 + l15) << 5) + rslot*8]); \
  } while (0)
#define MFMA16(nq) do { \
    __builtin_amdgcn_s_setprio(1); \
    _Pragma("unroll") \
    for (int mf_ = 0; mf_ < 8; mf_++) { \
      acc[mf_][(nq)*2+0] = __builtin_amdgcn_mfma_f32_16x16x32_bf16(af[mf_], bfr[0], acc[mf_][(nq)*2+0], 0, 0, 0); \
      acc[mf_][(nq)*2+1] = __builtin_amdgcn_mfma_f32_16x16x32_bf16(af[mf_], bfr[1], acc[mf_][(nq)*2+1], 0, 0, 0); \
    } \
    __builtin_amdgcn_s_setprio(0); \
  } while (0)

  // prologue: stage K-tile 0 fully (8 loads), publish A0/B0
  STAGE_A(0, 0, 0); STAGE_B(0, 0, 0);
  STAGE_A(0, 1, 32); STAGE_B(0, 1, 32);
  VMCNT(4);
  __builtin_amdgcn_s_barrier();

  for (int kt = 0; kt < 12; ++kt) {
    int db = kt & 1, dn = db ^ 1;
    int kof = (kt + 1) * 64;
    // ---- phase 0: nq=0, kk=0 ----
    if (kt < 11) STAGE_A(dn, 0, kof);
    LOAD_A(db, 0); LOAD_B(db, 0, 0);
    __builtin_amdgcn_s_barrier();
    MFMA16(0);
    // ---- phase 1: nq=1, kk=0 ----
    if (kt < 11) STAGE_B(dn, 0, kof);
    LOAD_B(db, 1, 0);
    if (kt < 11) { VMCNT(4); } else { VMCNT(0); }   // retire this tile's k1 chunks
    __builtin_amdgcn_s_barrier();
    MFMA16(1);
    // ---- phase 2: nq=0, kk=1 ----
    if (kt < 11) STAGE_A(dn, 1, kof + 32);
    LOAD_A(db, 1); LOAD_B(db, 0, 1);
    __builtin_amdgcn_s_barrier();
    MFMA16(0);
    // ---- phase 3: nq=1, kk=1 ----
    if (kt < 11) STAGE_B(dn, 1, kof + 32);
    LOAD_B(db, 1, 1);
    if (kt < 11) { VMCNT(4); }                      // retire next tile's k0 chunks
    __builtin_amdgcn_s_barrier();
    MFMA16(1);
  }

  // epilogue: which sub-matrix (q/k/v) is uniform per block (768 % 256 == 0)
  int which = n0 / DMODEL;
  #pragma unroll
  for (int nn = 0; nn < 4; nn++) {
    int col = n0 + wn * 64 + nn * 16 + l15;
    int hcol = col - which * DMODEL;
    int h = hcol >> 6, dh = hcol & 63;
    float bias = (which == 0) ? bq[hcol] : (which == 2 ? bv[hcol] : 0.f);
    #pragma unroll
    for (int mf = 0; mf < 8; mf++) {
      int rowb = m0 + wm * 128 + mf * 16 + (l4 << 2);
      #pragma unroll
      for (int r = 0; r < 4; r++) {
        int row = rowb + r;
        int b = row / SEQ;
        int s = row - b * SEQ;
        float v = acc[mf][nn][r] + bias;
        size_t bh = (size_t)b * NH + h;
        if (which == 0) {
          v *= 0.125f;  // fold 1/sqrt(64)
          qbuf[(bh * SEQ + s) * HD + dh] = f2bf(v);
        } else if (which == 1) {
          kbuf[(bh * SEQ + s) * HD + dh] = f2bf(v);
        } else {
          vbuf[(bh * HD + dh) * SP + s] = f2bf(v);  // transposed + padded
        }
      }
    }
  }
#undef STAGE_A
#undef STAGE_B
#undef LOAD_A
#undef LOAD_B
#undef MFMA16
}

// ---------------- fused windowed attention (swapped QK, 4 waves = 4 heads) ----
// block = (b, strip, head-group); 256 thr; mask strip in LDS shared by the 4
// heads; VGPR cap 128 (launch_bounds 256,4) -> ~8 loads in flight; 16 waves/CU.
// XCD b-affinity: b % 8 == xcd (mask/K/V L2 reuse).
#define AH 4
__global__ __launch_bounds__(256, 4)
void attn_kernel(const ushort* __restrict__ qbuf, const ushort* __restrict__ kbuf,
                 const ushort* __restrict__ vbuf, const float* __restrict__ mask,
                 const float* __restrict__ rbias, float* __restrict__ out) {
  __shared__ float mlds[16][164];                        // 10.25 KB mask strip
  __shared__ __align__(16) ushort plds[AH][16][SP + 8];  // per-wave P, 21 KB

  int id = blockIdx.x;
  int xcd = id & 7;
  int j = id >> 3;                 // 0..3839
  int b = xcd + 8 * (j / 30);      // b % 8 == xcd
  int rem = j % 30;
  int strip = rem / 3, hg = rem % 3;
  int r0 = strip * 16;

  int tid = threadIdx.x;
  int lane = tid & 63, w = tid >> 6;
  int h = hg * AH + w;             // wave -> head
  int l15 = lane & 15, l4 = lane >> 4;
  int bh = b * NH + h;

  const float* mp = mask + (size_t)b * SEQ * SEQ;

  // stage mask strip [16][164] (rows clamped, cols>=SEQ set to -3e38)
  for (int idx = tid; idx < 16 * 164; idx += 256) {
    int row = idx / 164, col = idx - row * 164;
    int gr = r0 + row; if (gr >= SEQ) gr = SEQ - 1;
    mlds[row][col] = (col < SEQ) ? mp[gr * SEQ + col] : -3e38f;
  }
  __syncthreads();

  int qi = r0 + l15;                       // this lane's query row
  int qc = (qi < SEQ) ? qi : (SEQ - 1);
  bool qok = (qi < SEQ);

  const ushort* qp = qbuf + (size_t)bh * SEQ * HD;
  const ushort* kp = kbuf + (size_t)bh * SEQ * HD;
  const ushort* vp = vbuf + (size_t)bh * HD * SP;
  const float* rp = rbias + (size_t)h * SEQ * RBS + (size_t)qc * RBS;

  // Q as the B-operand (col = qi)
  bf16x8 qf[2];
  if (qok) {
    qf[0] = *reinterpret_cast<const bf16x8*>(qp + qi * HD + l4 * 8);
    qf[1] = *reinterpret_cast<const bf16x8*>(qp + qi * HD + 32 + l4 * 8);
  } else {
    uint4 z = make_uint4(0, 0, 0, 0);
    qf[0] = *reinterpret_cast<bf16x8*>(&z);
    qf[1] = *reinterpret_cast<bf16x8*>(&z);
  }

  // scores: swapped mfma(K, Q) -> C[ki][qi]; lane holds 4 consecutive ki
  f32x4 sc[10];
  #pragma unroll
  for (int ct = 0; ct < 10; ct++)
    #pragma unroll
    for (int e = 0; e < 4; e++) sc[ct][e] = 0.f;
  #pragma unroll
  for (int ct = 0; ct < 10; ct++) {
    int krow = ct * 16 + l15;
    if (krow >= SEQ) krow = 0;   // clamp: real data, masked below
    bf16x8 kf0 = *reinterpret_cast<const bf16x8*>(kp + krow * HD + l4 * 8);
    bf16x8 kf1 = *reinterpret_cast<const bf16x8*>(kp + krow * HD + 32 + l4 * 8);
    sc[ct] = __builtin_amdgcn_mfma_f32_16x16x32_bf16(kf0, qf[0], sc[ct], 0, 0, 0);
    sc[ct] = __builtin_amdgcn_mfma_f32_16x16x32_bf16(kf1, qf[1], sc[ct], 0, 0, 0);
  }

  // add mask (LDS float4) + rel bias (global float4); per-lane max over ki
  float mx = -3e38f;
  #pragma unroll
  for (int ct = 0; ct < 10; ct++) {
    int kb = ct * 16 + l4 * 4;
    f32x4u rb = *reinterpret_cast<const f32x4u*>(rp + kb);
    f32x4u mk = *reinterpret_cast<const f32x4u*>(&mlds[l15][kb]);
    #pragma unroll
    for (int r = 0; r < 4; r++) {
      int ki = kb + r;
      float v = sc[ct][r] + mk[r] + rb[r];
      float sv = (ki < SEQ && qok) ? v : -3e38f;
      sc[ct][r] = sv;
      mx = fmaxf(mx, sv);
    }
  }
  mx = fmaxf(mx, __shfl_xor(mx, 16, 64));
  mx = fmaxf(mx, __shfl_xor(mx, 32, 64));

  // exp + sum over ki
  float sum = 0.f;
  #pragma unroll
  for (int ct = 0; ct < 10; ct++)
    #pragma unroll
    for (int r = 0; r < 4; r++) {
      float p = __expf(sc[ct][r] - mx);
      sc[ct][r] = p;
      sum += p;
    }
  sum += __shfl_xor(sum, 16, 64);
  sum += __shfl_xor(sum, 32, 64);
  float inv = 1.f / sum;

  // P (bf16) to per-wave LDS: row = qi idx (l15), cols = ki; ushort4 stores
  #pragma unroll
  for (int ct = 0; ct < 10; ct++) {
    ushort4 pk;
    pk.x = f2bf(sc[ct][0] * inv);
    pk.y = f2bf(sc[ct][1] * inv);
    pk.z = f2bf(sc[ct][2] * inv);
    pk.w = f2bf(sc[ct][3] * inv);
    *reinterpret_cast<ushort4*>(&plds[w][l15][ct * 16 + l4 * 4]) = pk;
  }

  // PV: ctx[16 x 64]; V^T direct from global (pad cols zeroed)
  #pragma unroll
  for (int ntl = 0; ntl < 4; ntl++) {
    f32x4 pacc;
    #pragma unroll
    for (int e = 0; e < 4; e++) pacc[e] = 0.f;
    #pragma unroll
    for (int ks = 0; ks < 5; ks++) {
      bf16x8 pa = *reinterpret_cast<const bf16x8*>(
          &plds[w][l15][ks * 32 + l4 * 8]);
      bf16x8 vb = *reinterpret_cast<const bf16x8*>(
          vp + (ntl * 16 + l15) * SP + ks * 32 + l4 * 8);
      pacc = __builtin_amdgcn_mfma_f32_16x16x32_bf16(pa, vb, pacc, 0, 0, 0);
    }
    #pragma unroll
    for (int r = 0; r < 4; r++) {
      int s = r0 + l4 * 4 + r;
      if (s < SEQ)
        out[((size_t)b * SEQ + s) * DMODEL + h * HD + ntl * 16 + l15] = pacc[r];
    }
  }
}

extern "C" void kernel_launch(void* const* d_in, const int* in_sizes, int n_in,
                              void* d_out, int out_size, void* d_ws, size_t ws_size,
                              hipStream_t stream) {
  const float* x    = (const float*)d_in[0];
  const float* mask = (const float*)d_in[1];
  const float* Wq   = (const float*)d_in[2];
  const float* bq   = (const float*)d_in[3];
  const float* Wk   = (const float*)d_in[4];
  const float* Wv   = (const float*)d_in[5];
  const float* bv   = (const float*)d_in[6];
  const float* tbl  = (const float*)d_in[7];
  float* out = (float*)d_out;

  char* ws = (char*)d_ws;
  ushort* Wt = (ushort*)ws;                         // 3,538,944 B
  size_t off = (size_t)NTOT * DMODEL * 2;
  ushort* qbuf = (ushort*)(ws + off); off += (size_t)BDIM * NH * SEQ * HD * 2;
  ushort* kbuf = (ushort*)(ws + off); off += (size_t)BDIM * NH * SEQ * HD * 2;
  ushort* vbuf = (ushort*)(ws + off); off += (size_t)BDIM * NH * HD * SP * 2;
  float*  rbias = (float*)(ws + off); off += (size_t)NH * SEQ * RBS * 4 + 64;
  // ~713 MB of d_ws

  // bf16 x lives in d_out scratch (456 MB f32 out >= 228 MB bf16 x);
  // attn_kernel later overwrites every element of d_out.
  ushort* xbuf = (ushort*)d_out;

  prep_w<<<(NTOT * DMODEL + 255) / 256, 256, 0, stream>>>(Wq, Wk, Wv, Wt);
  zero_vpad<<<(BDIM * NH * HD * (SP - SEQ) + 255) / 256, 256, 0, stream>>>(vbuf);
  rel_prep<<<(NH * SEQ * RBS + 255) / 256, 256, 0, stream>>>(tbl, rbias);
  {
    size_t total = (size_t)BDIM * SEQ * DMODEL;
    x2bf<<<(int)(total / 8 / 256), 256, 0, stream>>>(x, xbuf);
  }

  qkv_gemm<<<GNWG, 512, 0, stream>>>(xbuf, Wt, bq, bv, qbuf, kbuf, vbuf);

  attn_kernel<<<BDIM * 10 * 3, 256, 0, stream>>>(qbuf, kbuf, vbuf, mask, rbias, out);
}

// Round 10
// 1630.840 us; speedup vs baseline: 1.2738x; 1.0354x over previous
//
#include <hip/hip_runtime.h>
#include <hip/hip_bf16.h>

typedef __bf16 bf16x8 __attribute__((ext_vector_type(8)));
typedef float f32x4 __attribute__((ext_vector_type(4)));
typedef float f32x4u __attribute__((ext_vector_type(4), aligned(4)));

#define NH 12
#define HD 64
#define SEQ 145
#define SP 160
#define DMODEL 768
#define NTOT 2304
#define BDIM 1024
#define RBS 148   // rbias padded row stride (4-aligned float4 rows)

// f32 -> bf16 RNE
__device__ __forceinline__ ushort f2bf(float f) {
  union { float f; uint u; } a; a.f = f;
  uint u = a.u;
  return (ushort)((u + 0x7FFFu + ((u >> 16) & 1u)) >> 16);
}

__device__ __forceinline__ int relidx(int qi, int ki) {
  if (ki == 0) return (qi == 0) ? 531 : 530;
  if (qi == 0) return 529;
  int q = qi - 1, k = ki - 1;
  int qh = q / 12, qw = q - qh * 12;
  int kh = k / 12, kw = k - kh * 12;
  return (qh - kh + 11) * 23 + (qw - kw + 11);
}

// async global->LDS, 16B per lane; lds dest = wave-uniform base + lane*16
__device__ __forceinline__ void gload_lds16(const ushort* g, ushort* l) {
  __builtin_amdgcn_global_load_lds(
      (const __attribute__((address_space(1))) void*)g,
      (__attribute__((address_space(3))) void*)l, 16, 0, 0);
}

#define VMCNT(n) do { asm volatile("s_waitcnt vmcnt(" #n ")" ::: "memory"); \
                      __builtin_amdgcn_sched_barrier(0); } while (0)

// ---------------- prep: Wt[n][k] = W_sel[k][n%768] as bf16 ----------------
__global__ void prep_w(const float* __restrict__ Wq, const float* __restrict__ Wk,
                       const float* __restrict__ Wv, ushort* __restrict__ Wt) {
  int i = blockIdx.x * 256 + threadIdx.x;
  if (i >= NTOT * DMODEL) return;
  int n = i / DMODEL, k = i - n * DMODEL;
  const float* W = (n < DMODEL) ? Wq : (n < 2 * DMODEL ? Wk : Wv);
  int c = n % DMODEL;
  Wt[i] = f2bf(W[k * DMODEL + c]);
}

// ---------------- x f32 -> bf16 (into d_out scratch) ----------------
__global__ void x2bf(const float* __restrict__ x, ushort* __restrict__ xb) {
  const size_t total = (size_t)BDIM * SEQ * DMODEL;
  size_t i = ((size_t)blockIdx.x * 256 + threadIdx.x) * 8;
  if (i >= total) return;
  float4 a = *reinterpret_cast<const float4*>(x + i);
  float4 c = *reinterpret_cast<const float4*>(x + i + 4);
  uint4 o;
  o.x = (uint)f2bf(a.x) | ((uint)f2bf(a.y) << 16);
  o.y = (uint)f2bf(a.z) | ((uint)f2bf(a.w) << 16);
  o.z = (uint)f2bf(c.x) | ((uint)f2bf(c.y) << 16);
  o.w = (uint)f2bf(c.z) | ((uint)f2bf(c.w) << 16);
  *reinterpret_cast<uint4*>(xb + i) = o;
}

// ---------------- zero pad region of transposed V buffer ----------------
__global__ void zero_vpad(ushort* __restrict__ vbuf) {
  int i = blockIdx.x * 256 + threadIdx.x;
  const int total = BDIM * NH * HD * (SP - SEQ);
  if (i >= total) return;
  int s = SEQ + i % (SP - SEQ);
  int row = i / (SP - SEQ);
  vbuf[(size_t)row * SP + s] = 0;
}

// ---------------- rel bias table: rbias[h][qi][ki], row stride RBS ----------------
__global__ void rel_prep(const float* __restrict__ tbl, float* __restrict__ rbias) {
  int i = blockIdx.x * 256 + threadIdx.x;
  if (i >= NH * SEQ * RBS) return;
  int h = i / (SEQ * RBS);
  int rem = i - h * SEQ * RBS;
  int qi = rem / RBS, ki = rem - qi * RBS;
  rbias[i] = (ki < SEQ) ? tbl[relidx(qi, ki) * NH + h] : 0.f;
}

// ---------------- fused QKV GEMM: [148480,768] x [768,2304] ----------------
// 128x256 tile, 8 waves (2x4), per-wave 64x64 (acc 64 VGPR, ~110 total);
// BK=32 double-buffered = 48 KB LDS -> 2 blocks/CU (16 waves). Single-phase:
// STAGE(next) -> ds_read(cur) -> MFMA -> vmcnt(0) -> barrier. Swizzled LDS.
#define GNT 9
#define GNWG 10440   // 1160 * 9
#define NKT 24       // 768 / 32

__global__ __launch_bounds__(512, 4)
void qkv_gemm(const ushort* __restrict__ xb, const ushort* __restrict__ Wt,
              const float* __restrict__ bq, const float* __restrict__ bv,
              ushort* __restrict__ qbuf, ushort* __restrict__ kbuf,
              ushort* __restrict__ vbuf) {
  __shared__ __align__(16) ushort lds[24576];  // 48 KB: A[2][4096] | B[2][8192]

  int bid = blockIdx.x;
  int logical = (bid & 7) * 1305 + (bid >> 3);   // 10440 % 8 == 0, bijective
  int mt = logical / GNT, nt = logical - (logical / GNT) * GNT;
  int m0 = mt * 128, n0 = nt * 256;

  int tid = threadIdx.x;
  int l = tid & 63, w = tid >> 6;
  int wm = w >> 2, wn = w & 3;          // 2 x 4 wave grid
  int l15 = l & 15, l4 = l >> 4;
  int rslot = l4 ^ ((l15 >> 1) & 3);    // read-side swizzle (BK=32: 4 slots)

  // staging: thread t -> row (t>>2), stored slot (t&3); src chunk inverse-swz
  int srow = tid >> 2;                  // 0..127
  int schunk = (tid & 3) ^ ((tid >> 3) & 3);
  const ushort* aSrc  = xb + (size_t)(m0 + srow) * DMODEL + schunk * 8;
  const ushort* bSrc0 = Wt + (size_t)(n0 + srow) * DMODEL + schunk * 8;
  const ushort* bSrc1 = Wt + (size_t)(n0 + 128 + srow) * DMODEL + schunk * 8;
  int wdst = w << 9;   // w*512 ushorts (wave-contiguous dest)

#define STAGE(db, kof) do { \
    gload_lds16(aSrc  + (kof), &lds[((db) << 12) + wdst]); \
    gload_lds16(bSrc0 + (kof), &lds[8192 + ((db) << 13) + wdst]); \
    gload_lds16(bSrc1 + (kof), &lds[8192 + ((db) << 13) + 4096 + wdst]); \
  } while (0)

  f32x4 acc[4][4];
  #pragma unroll
  for (int m = 0; m < 4; m++)
    #pragma unroll
    for (int n = 0; n < 4; n++)
      #pragma unroll
      for (int e = 0; e < 4; e++) acc[m][n][e] = 0.f;

  bf16x8 af[4], bfv[4];

#define LOADFRAG(db) do { \
    int ab_ = (db) << 12, bb_ = 8192 + ((db) << 13); \
    _Pragma("unroll") \
    for (int i_ = 0; i_ < 4; i_++) \
      af[i_] = *reinterpret_cast<const bf16x8*>( \
          &lds[ab_ + ((wm * 64 + i_ * 16 + l15) << 5) + rslot * 8]); \
    _Pragma("unroll") \
    for (int n_ = 0; n_ < 4; n_++) \
      bfv[n_] = *reinterpret_cast<const bf16x8*>( \
          &lds[bb_ + ((wn * 64 + n_ * 16 + l15) << 5) + rslot * 8]); \
  } while (0)
#define MFMA16() do { \
    __builtin_amdgcn_s_setprio(1); \
    _Pragma("unroll") \
    for (int i_ = 0; i_ < 4; i_++) \
      _Pragma("unroll") \
      for (int n_ = 0; n_ < 4; n_++) \
        acc[i_][n_] = __builtin_amdgcn_mfma_f32_16x16x32_bf16( \
            af[i_], bfv[n_], acc[i_][n_], 0, 0, 0); \
    __builtin_amdgcn_s_setprio(0); \
  } while (0)

  // prologue: stage tile 0
  STAGE(0, 0);
  VMCNT(0);
  __builtin_amdgcn_s_barrier();

  #pragma unroll 2
  for (int t = 0; t < NKT; ++t) {
    int db = t & 1, dn = db ^ 1;
    if (t < NKT - 1) STAGE(dn, (t + 1) * 32);   // issue next tile first
    LOADFRAG(db);                                // cur tile (published last iter)
    MFMA16();                                    // lgkmcnt waits auto-inserted
    if (t < NKT - 1) {
      VMCNT(0);                                  // retire dn staging
      __builtin_amdgcn_s_barrier();              // publish dn, fence db reads
    }
  }

  // epilogue
  int which = n0 / DMODEL;
  int h_[4], dh_[4];
  float bias_[4];
  #pragma unroll
  for (int nn = 0; nn < 4; nn++) {
    int col = n0 + wn * 64 + nn * 16 + l15;
    int hcol = col - which * DMODEL;
    h_[nn] = hcol >> 6; dh_[nn] = hcol & 63;
    bias_[nn] = (which == 0) ? bq[hcol] : (which == 2 ? bv[hcol] : 0.f);
  }
  #pragma unroll
  for (int i = 0; i < 4; i++) {
    #pragma unroll
    for (int r = 0; r < 4; r++) {
      int row = m0 + wm * 64 + i * 16 + (l4 << 2) + r;
      int b = row / SEQ;
      int s = row - b * SEQ;
      #pragma unroll
      for (int nn = 0; nn < 4; nn++) {
        float v = acc[i][nn][r] + bias_[nn];
        size_t bh = (size_t)b * NH + h_[nn];
        if (which == 0) {
          v *= 0.125f;  // fold 1/sqrt(64)
          qbuf[(bh * SEQ + s) * HD + dh_[nn]] = f2bf(v);
        } else if (which == 1) {
          kbuf[(bh * SEQ + s) * HD + dh_[nn]] = f2bf(v);
        } else {
          vbuf[(bh * HD + dh_[nn]) * SP + s] = f2bf(v);  // transposed + padded
        }
      }
    }
  }
#undef STAGE
#undef LOADFRAG
#undef MFMA16
}

// ---------------- fused windowed attention (swapped QK, no LDS sync) --------
// block = (b, strip, head-group of 4); 256 thr; NO barriers - mask read as
// coalesced float4 straight from L2 (b%8==xcd affinity). plds per-wave only.
#define AH 4
__global__ __launch_bounds__(256, 4)
void attn_kernel(const ushort* __restrict__ qbuf, const ushort* __restrict__ kbuf,
                 const ushort* __restrict__ vbuf, const float* __restrict__ mask,
                 const float* __restrict__ rbias, float* __restrict__ out) {
  __shared__ __align__(16) ushort plds[AH][16][SP + 8];  // 21 KB

  int id = blockIdx.x;
  int xcd = id & 7;
  int j = id >> 3;                 // 0..3839
  int b = xcd + 8 * (j / 30);      // b % 8 == xcd
  int rem = j % 30;
  int strip = rem / 3, hg = rem % 3;
  int r0 = strip * 16;

  int tid = threadIdx.x;
  int lane = tid & 63, w = tid >> 6;
  int h = hg * AH + w;             // wave -> head
  int l15 = lane & 15, l4 = lane >> 4;
  int bh = b * NH + h;

  int qi = r0 + l15;                       // this lane's query row
  int qc = (qi < SEQ) ? qi : (SEQ - 1);
  bool qok = (qi < SEQ);

  const ushort* qp = qbuf + (size_t)bh * SEQ * HD;
  const ushort* kp = kbuf + (size_t)bh * SEQ * HD;
  const ushort* vp = vbuf + (size_t)bh * HD * SP;
  const float* mrow = mask + (size_t)b * SEQ * SEQ + (size_t)qc * SEQ;
  const float* rp = rbias + (size_t)h * SEQ * RBS + (size_t)qc * RBS;

  // Q as the B-operand (col = qi)
  bf16x8 qf[2];
  if (qok) {
    qf[0] = *reinterpret_cast<const bf16x8*>(qp + qi * HD + l4 * 8);
    qf[1] = *reinterpret_cast<const bf16x8*>(qp + qi * HD + 32 + l4 * 8);
  } else {
    uint4 z = make_uint4(0, 0, 0, 0);
    qf[0] = *reinterpret_cast<bf16x8*>(&z);
    qf[1] = *reinterpret_cast<bf16x8*>(&z);
  }

  // scores: swapped mfma(K, Q) -> C[ki][qi]; lane holds 4 consecutive ki
  f32x4 sc[10];
  #pragma unroll
  for (int ct = 0; ct < 10; ct++)
    #pragma unroll
    for (int e = 0; e < 4; e++) sc[ct][e] = 0.f;
  #pragma unroll
  for (int ct = 0; ct < 10; ct++) {
    int krow = ct * 16 + l15;
    if (krow >= SEQ) krow = 0;   // clamp: real data, masked below
    bf16x8 kf0 = *reinterpret_cast<const bf16x8*>(kp + krow * HD + l4 * 8);
    bf16x8 kf1 = *reinterpret_cast<const bf16x8*>(kp + krow * HD + 32 + l4 * 8);
    sc[ct] = __builtin_amdgcn_mfma_f32_16x16x32_bf16(kf0, qf[0], sc[ct], 0, 0, 0);
    sc[ct] = __builtin_amdgcn_mfma_f32_16x16x32_bf16(kf1, qf[1], sc[ct], 0, 0, 0);
  }

  // mask + rel bias as float4 rows (ct 0..8 fully in-bounds: kb+3 <= 143)
  float mx = -3e38f;
  #pragma unroll
  for (int ct = 0; ct < 9; ct++) {
    int kb = ct * 16 + l4 * 4;
    f32x4u rb = *reinterpret_cast<const f32x4u*>(rp + kb);
    f32x4u mk = *reinterpret_cast<const f32x4u*>(mrow + kb);
    #pragma unroll
    for (int r = 0; r < 4; r++) {
      float v = sc[ct][r] + mk[r] + rb[r];
      float sv = qok ? v : -3e38f;
      sc[ct][r] = sv;
      mx = fmaxf(mx, sv);
    }
  }
  // ct 9: ki = 144 + l4*4 + r; only ki==144 (l4==0, r==0) is valid
  {
    float sv = -3e38f;
    if (l4 == 0 && qok) sv = sc[9][0] + mrow[144] + rp[144];
    sc[9][0] = sv;
    sc[9][1] = -3e38f; sc[9][2] = -3e38f; sc[9][3] = -3e38f;
    mx = fmaxf(mx, sv);
  }
  mx = fmaxf(mx, __shfl_xor(mx, 16, 64));
  mx = fmaxf(mx, __shfl_xor(mx, 32, 64));

  // exp + sum over ki
  float sum = 0.f;
  #pragma unroll
  for (int ct = 0; ct < 10; ct++)
    #pragma unroll
    for (int r = 0; r < 4; r++) {
      float p = __expf(sc[ct][r] - mx);
      sc[ct][r] = p;
      sum += p;
    }
  sum += __shfl_xor(sum, 16, 64);
  sum += __shfl_xor(sum, 32, 64);
  float inv = 1.f / sum;

  // P (bf16) to per-wave LDS: row = qi idx (l15), cols = ki; ushort4 stores
  #pragma unroll
  for (int ct = 0; ct < 10; ct++) {
    ushort4 pk;
    pk.x = f2bf(sc[ct][0] * inv);
    pk.y = f2bf(sc[ct][1] * inv);
    pk.z = f2bf(sc[ct][2] * inv);
    pk.w = f2bf(sc[ct][3] * inv);
    *reinterpret_cast<ushort4*>(&plds[w][l15][ct * 16 + l4 * 4]) = pk;
  }

  // PV: ctx[16 x 64]; V^T direct from global (pad cols zeroed)
  #pragma unroll
  for (int ntl = 0; ntl < 4; ntl++) {
    f32x4 pacc;
    #pragma unroll
    for (int e = 0; e < 4; e++) pacc[e] = 0.f;
    #pragma unroll
    for (int ks = 0; ks < 5; ks++) {
      bf16x8 pa = *reinterpret_cast<const bf16x8*>(
          &plds[w][l15][ks * 32 + l4 * 8]);
      bf16x8 vb = *reinterpret_cast<const bf16x8*>(
          vp + (ntl * 16 + l15) * SP + ks * 32 + l4 * 8);
      pacc = __builtin_amdgcn_mfma_f32_16x16x32_bf16(pa, vb, pacc, 0, 0, 0);
    }
    #pragma unroll
    for (int r = 0; r < 4; r++) {
      int s = r0 + l4 * 4 + r;
      if (s < SEQ)
        out[((size_t)b * SEQ + s) * DMODEL + h * HD + ntl * 16 + l15] = pacc[r];
    }
  }
}

extern "C" void kernel_launch(void* const* d_in, const int* in_sizes, int n_in,
                              void* d_out, int out_size, void* d_ws, size_t ws_size,
                              hipStream_t stream) {
  const float* x    = (const float*)d_in[0];
  const float* mask = (const float*)d_in[1];
  const float* Wq   = (const float*)d_in[2];
  const float* bq   = (const float*)d_in[3];
  const float* Wk   = (const float*)d_in[4];
  const float* Wv   = (const float*)d_in[5];
  const float* bv   = (const float*)d_in[6];
  const float* tbl  = (const float*)d_in[7];
  float* out = (float*)d_out;

  char* ws = (char*)d_ws;
  ushort* Wt = (ushort*)ws;                         // 3,538,944 B
  size_t off = (size_t)NTOT * DMODEL * 2;
  ushort* qbuf = (ushort*)(ws + off); off += (size_t)BDIM * NH * SEQ * HD * 2;
  ushort* kbuf = (ushort*)(ws + off); off += (size_t)BDIM * NH * SEQ * HD * 2;
  ushort* vbuf = (ushort*)(ws + off); off += (size_t)BDIM * NH * HD * SP * 2;
  float*  rbias = (float*)(ws + off); off += (size_t)NH * SEQ * RBS * 4 + 64;
  // ~713 MB of d_ws

  // bf16 x lives in d_out scratch (456 MB f32 out >= 228 MB bf16 x);
  // attn_kernel later overwrites every element of d_out.
  ushort* xbuf = (ushort*)d_out;

  prep_w<<<(NTOT * DMODEL + 255) / 256, 256, 0, stream>>>(Wq, Wk, Wv, Wt);
  zero_vpad<<<(BDIM * NH * HD * (SP - SEQ) + 255) / 256, 256, 0, stream>>>(vbuf);
  rel_prep<<<(NH * SEQ * RBS + 255) / 256, 256, 0, stream>>>(tbl, rbias);
  {
    size_t total = (size_t)BDIM * SEQ * DMODEL;
    x2bf<<<(int)(total / 8 / 256), 256, 0, stream>>>(x, xbuf);
  }

  qkv_gemm<<<GNWG, 512, 0, stream>>>(xbuf, Wt, bq, bv, qbuf, kbuf, vbuf);

  attn_kernel<<<BDIM * 10 * 3, 256, 0, stream>>>(qbuf, kbuf, vbuf, mask, rbias, out);
}